// Round 26
// baseline (147.976 us; speedup 1.0000x reference)
//
#include <hip/hip_runtime.h>
#include <hip/hip_bf16.h>

// SpatialCrossAttention (BEVFormer SCA) fused pipeline for MI355X/gfx950.
//  K0 detect    : infer bev_mask storage layout (u8 / i32 / f32)
//  K1 prep_hit  : FUSED: tables + bias | hit/invcnt | NEW: value->fp8 cvt
//  K2 gemm_v_oa : FUSED: gemm_v now reads FP8 A (u64/kc, no pack VALU;
//                 A-traffic 142.5->35.6MB = the one quantity that has tracked
//                 gemm_v dur in every variant) | gemm_oa bf16 quarter-staged
//  K3 sample    : head-pinned blocks; 4-lane units + u64 loads (measured)
//  K4 gemm_out  : bf16 quarter-staged + residual

__device__ __forceinline__ void gload_lds16(const void* g, void* l) {
    __builtin_amdgcn_global_load_lds(
        (const __attribute__((address_space(1))) unsigned*)g,
        (__attribute__((address_space(3))) unsigned*)l, 16, 0, 0);
}

typedef __attribute__((ext_vector_type(8))) short short8;
typedef __attribute__((ext_vector_type(4))) float f32x4;
typedef __attribute__((ext_vector_type(2))) float floatx2;

__device__ __forceinline__ short f2bf(float f) {
    union { float f; unsigned u; } c; c.f = f;
    unsigned u = c.u;
    unsigned r = (u + 0x7FFFu + ((u >> 16) & 1u)) >> 16;  // RNE
    return (short)r;
}

// ---- fp8 e4m3fn decode/encode: HW cvt on gfx950, manual fallback ----
__device__ __forceinline__ float e4m3f_manual(unsigned b) {
    unsigned s = (b & 0x80u) << 24;
    unsigned e = (b >> 3) & 15u;
    unsigned m = b & 7u;
    if (e) return __uint_as_float(s | ((e + 120u) << 23) | (m << 20));
    return __uint_as_float(s | __float_as_uint((float)m * 0x1p-9f));
}
__device__ __forceinline__ unsigned char f2e4m3_manual(float x) {
    unsigned u = __float_as_uint(x);
    unsigned s = (u >> 24) & 0x80u;
    float ax = fabsf(x);
    if (!(ax > 0x1p-10f)) return (unsigned char)s;
    if (ax >= 440.f) return (unsigned char)(s | 0x7Eu);
    unsigned au = u & 0x7FFFFFFFu;
    int e = (int)(au >> 23) - 127;
    if (e >= -6) {
        unsigned r = au + 0x7FFFFu + ((au >> 20) & 1u);
        e = (int)(r >> 23) - 127;
        unsigned m = (r >> 20) & 7u;
        if (e > 8) return (unsigned char)(s | 0x7Eu);
        return (unsigned char)(s | (unsigned)((e + 7) << 3) | m);
    } else {
        int m = (int)rintf(ax * 512.f);
        return (unsigned char)(s | (unsigned)m);
    }
}
__device__ __forceinline__ unsigned char enc_fp8(float v) {
#if __has_builtin(__builtin_amdgcn_cvt_pk_fp8_f32)
    return (unsigned char)(__builtin_amdgcn_cvt_pk_fp8_f32(v, v, 0, false) & 0xFF);
#else
    return f2e4m3_manual(v);
#endif
}
__device__ __forceinline__ unsigned pk4fp8(float4 x) {
#if __has_builtin(__builtin_amdgcn_cvt_pk_fp8_f32)
    unsigned pk = (unsigned)__builtin_amdgcn_cvt_pk_fp8_f32(x.x, x.y, 0, false);
    pk = (unsigned)__builtin_amdgcn_cvt_pk_fp8_f32(x.z, x.w, (int)pk, true);
    return pk;
#else
    return (unsigned)f2e4m3_manual(x.x) | ((unsigned)f2e4m3_manual(x.y) << 8)
         | ((unsigned)f2e4m3_manual(x.z) << 16) | ((unsigned)f2e4m3_manual(x.w) << 24);
#endif
}

static constexpr int QN   = 10000;
static constexpr int CAMS = 6;
static constexpr int NV   = 23200;   // 116*200
static constexpr int HH   = 116;
static constexpr int WW   = 200;
static constexpr int MROW = CAMS * NV;  // 139200
static constexpr int TABE = 65536;      // entries per table copy
static constexpr int NVB  = (MROW + 127) / 128;    // 1088 gemm_v blocks
static constexpr int NOAB = (QN + 127) / 128;      // 79 gemm_oa blocks
static constexpr int NPREP = 769;                  // prep blocks
static constexpr int NHIT  = (QN + 255) / 256;     // 40 hit blocks
static constexpr int NCVT  = MROW * 256 / 4 / 256; // 34800 cvt blocks

// ---------------- K0: mask layout detect (16KB scan) ----------------
__global__ void detect_kernel(const unsigned char* __restrict__ mask, int* __restrict__ flag) {
    __shared__ unsigned s12[256], s3[256];
    unsigned o12 = 0, o3 = 0;
    for (int i = threadIdx.x; i < 16384; i += 256) {
        unsigned char b = mask[i];
        int m = i & 3;
        if (m == 1 || m == 2) o12 |= b;
        else if (m == 3) o3 |= b;
    }
    s12[threadIdx.x] = o12; s3[threadIdx.x] = o3;
    __syncthreads();
    if (threadIdx.x == 0) {
        unsigned a = 0, b = 0;
        for (int i = 0; i < 256; i++) { a |= s12[i]; b |= s3[i]; }
        *flag = a ? 0 : (b ? 2 : 1);  // 0=u8, 1=i32, 2=f32
    }
}

// ---------------- K1: FUSED prep | hit | value->fp8 cvt ----------------
__global__ void prep_hit_kernel(const float* __restrict__ wv, const float* __restrict__ woff,
                                const float* __restrict__ wattn, const float* __restrict__ wout,
                                const float* __restrict__ boff, const float* __restrict__ battn,
                                unsigned char* __restrict__ tv8, short* __restrict__ toa,
                                short* __restrict__ tout, float* __restrict__ biasOA,
                                const void* __restrict__ mask, const int* __restrict__ flag,
                                float* __restrict__ hit, float* __restrict__ invcnt,
                                const float* __restrict__ value, unsigned* __restrict__ value8) {
    int bid = blockIdx.x;
    if (bid < NPREP) {
        int id = bid * 256 + threadIdx.x;
        if (id < 3 * TABE) {
            int t = id >> 16;
            int e = id & 65535;
            int j = e & 7, l = (e >> 3) & 63, nt = (e >> 9) & 15, kc = e >> 13;
            int k = kc * 32 + ((l >> 4) << 3) + j;
            int col = nt * 16 + (l & 15);
            if (t == 0) {
                unsigned char b = enc_fp8(wv[k * 256 + col]);
                #pragma unroll
                for (int c = 0; c < 8; c++) tv8[c * TABE + e] = b;
            } else {
                float v;
                if (t == 1) v = (col < 128) ? woff[k * 128 + col]
                                  : (col < 192 ? wattn[k * 64 + (col - 128)] : 0.f);
                else        v = wout[k * 256 + col];
                short* dst = (t == 1) ? toa : tout;
                short bv = f2bf(v);
                #pragma unroll
                for (int c = 0; c < 8; c++) dst[c * TABE + e] = bv;
            }
        } else {
            int i = id - 3 * TABE;
            if (i < 192) biasOA[i] = (i < 128) ? boff[i] : battn[i - 128];
        }
    } else if (bid < NPREP + NHIT) {
        int q = (bid - NPREP) * 256 + threadIdx.x;
        if (q >= QN) return;
        int f = *flag;
        int cnt = 0;
        for (int c = 0; c < CAMS; c++) {
            bool any = false;
            #pragma unroll
            for (int d = 0; d < 4; d++) {
                size_t i = (size_t)(c * QN + q) * 4 + d;
                bool b;
                if (f == 0)      b = ((const unsigned char*)mask)[i] != 0;
                else if (f == 1) b = ((const int*)mask)[i] != 0;
                else             b = ((const float*)mask)[i] != 0.f;
                any |= b;
            }
            hit[c * QN + q] = any ? 1.f : 0.f;
            cnt += any ? 1 : 0;
        }
        invcnt[q] = 1.f / (float)(cnt > 0 ? cnt : 1);
    } else {
        // value -> fp8: thread t converts 4 consecutive floats (coalesced)
        size_t t = (size_t)(bid - NPREP - NHIT) * 256 + threadIdx.x;
        float4 x = *(const float4*)(value + t * 4);
        value8[t] = pk4fp8(x);
    }
}

__device__ __forceinline__ short8 cvt8(float4 x0, float4 x1) {
    unsigned u0, u1, u2, u3;
    asm("v_cvt_pk_bf16_f32 %0, %1, %2" : "=v"(u0) : "v"(x0.x), "v"(x0.y));
    asm("v_cvt_pk_bf16_f32 %0, %1, %2" : "=v"(u1) : "v"(x0.z), "v"(x0.w));
    asm("v_cvt_pk_bf16_f32 %0, %1, %2" : "=v"(u2) : "v"(x1.x), "v"(x1.y));
    asm("v_cvt_pk_bf16_f32 %0, %1, %2" : "=v"(u3) : "v"(x1.z), "v"(x1.w));
    union { unsigned u[4]; short8 s8; } uu;
    uu.u[0] = u0; uu.u[1] = u1; uu.u[2] = u2; uu.u[3] = u3;
    return uu.s8;
}

// ---------------- K2: FUSED gemm_v (fp8 A) + gemm_oa -------------------------
__global__ __launch_bounds__(512)
void gemm_v_oa(const unsigned char* __restrict__ A8, const unsigned char* __restrict__ Wtab8,
               const float* __restrict__ biasV,
               const float* __restrict__ Q, const short* __restrict__ WtabOA,
               const float* __restrict__ biasOA,
               void* __restrict__ vout, void* __restrict__ oaout, int M) {
    __shared__ __align__(16) char smem[65536];
    const int tid = threadIdx.x;
    const int l  = tid & 63;
    const int wv = tid >> 6;
    const int lr = l & 15;
    const int lg = l >> 4;

    if (blockIdx.x < NVB) {
        // ---------------- gemm_v body: fp8 A (u64 per kc) --------------------
        unsigned char* tab = (unsigned char*)smem;
        const int mBase = (blockIdx.x * 8 + wv) * 16;
        const int mRow = mBase + lr;
        const int m = min(mRow, M - 1);
        const unsigned char* wsrc = Wtab8 + (size_t)(blockIdx.x & 7) * TABE;

        #pragma unroll
        for (int it = 0; it < 8; it++) {
            gload_lds16(wsrc + (it * 512 + tid) * 16,
                        tab + it * 8192 + (tid & 448) * 16);   // wave-uniform dst
        }

        const unsigned char* arow = A8 + (size_t)m * 256 + lg * 8;
        f32x4 acc[16] = {};

        long long a0, b0;
        a0 = *(const long long*)(arow);
        __syncthreads();                            // table visible; ONLY barrier

        auto stepKC = [&](int kc, long long bfrag) {
            #pragma unroll
            for (int nt = 0; nt < 16; nt++) {
                long long wf = *(const long long*)(&tab[(kc * 16 + nt) * 512 + l * 8]);
                acc[nt] = __builtin_amdgcn_mfma_f32_16x16x32_fp8_fp8(wf, bfrag, acc[nt], 0, 0, 0);
            }
        };

        #pragma unroll
        for (int kc = 0; kc < 8; kc += 2) {
            if (kc + 1 < 8) b0 = *(const long long*)(arow + (kc + 1) * 32);
            stepKC(kc, a0);
            if (kc + 2 < 8) a0 = *(const long long*)(arow + (kc + 2) * 32);
            stepKC(kc + 1, b0);
        }

        if (mRow < M) {
            #pragma unroll
            for (int nt = 0; nt < 16; nt++) {
                int n0 = nt * 16 + lg * 4;
                float4 bv = *(const float4*)(biasV + n0);
                float4 x;
                x.x = acc[nt][0] + bv.x; x.y = acc[nt][1] + bv.y;
                x.z = acc[nt][2] + bv.z; x.w = acc[nt][3] + bv.w;
                unsigned pk = pk4fp8(x);
                // head-planar: plane nt>>1, slot (nt&1)*4+lg of row mRow
                ((unsigned*)vout)[(size_t)(nt >> 1) * MROW * 8 + (size_t)mRow * 8
                                  + (nt & 1) * 4 + lg] = pk;
            }
        }
    } else {
        // ---------------- gemm_oa body (bf16, quarter-staged, 192 cols) ------
        short (*tab)[16384] = (short (*)[16384])smem;
        const int bid = blockIdx.x - NVB;
        const int mBase = (bid * 8 + wv) * 16;
        const int mRow = mBase + lr;
        const int m = min(mRow, QN - 1);
        const char* wsrc = (const char*)WtabOA + (size_t)(bid & 7) * (TABE * 2);

        auto load_q = [&](int b, int q) {
            #pragma unroll
            for (int it = 0; it < 4; it++) {
                int linear = (it * 512 + tid) * 16;
                const char* src = wsrc + q * 32768 + linear;
                char* dst = (char*)&tab[b][0] + it * 8192 + (tid & 448) * 16;
                gload_lds16(src, dst);
            }
        };

        f32x4 acc[12] = {};
        const float* arow = Q + (size_t)m * 256 + lg * 8;

        auto loadAkc = [&](int kc, float4& x0, float4& x1) {
            const float4* p = (const float4*)(arow + kc * 32);
            x0 = p[0]; x1 = p[1];
        };
        auto stepKC = [&](int b, int kk, float4 x0, float4 x1) {
            short8 bfrag = cvt8(x0, x1);
            #pragma unroll
            for (int nt = 0; nt < 12; nt++) {
                short8 wf = *(const short8*)(&tab[b][(kk * 16 + nt) * 512 + l * 8]);
                acc[nt] = __builtin_amdgcn_mfma_f32_16x16x32_bf16(wf, bfrag, acc[nt], 0, 0, 0);
            }
        };

        float4 a0, a1, b0, b1;
        loadAkc(0, a0, a1);
        load_q(0, 0);
        __syncthreads();
        load_q(1, 1);

        loadAkc(1, b0, b1);  stepKC(0, 0, a0, a1);
        loadAkc(2, a0, a1);  stepKC(0, 1, b0, b1);
        __syncthreads();
        load_q(0, 2);
        loadAkc(3, b0, b1);  stepKC(1, 0, a0, a1);
        loadAkc(4, a0, a1);  stepKC(1, 1, b0, b1);
        __syncthreads();
        load_q(1, 3);
        loadAkc(5, b0, b1);  stepKC(0, 0, a0, a1);
        loadAkc(6, a0, a1);  stepKC(0, 1, b0, b1);
        __syncthreads();
        loadAkc(7, b0, b1);  stepKC(1, 0, a0, a1);
                             stepKC(1, 1, b0, b1);

        if (mRow < QN) {
            #pragma unroll
            for (int nt = 0; nt < 12; nt++) {
                int n0 = nt * 16 + lg * 4;
                float4 bv = *(const float4*)(biasOA + n0);
                float4 o;
                o.x = acc[nt][0] + bv.x; o.y = acc[nt][1] + bv.y;
                o.z = acc[nt][2] + bv.z; o.w = acc[nt][3] + bv.w;
                *(float4*)((float*)oaout + (size_t)mRow * 192 + n0) = o;
            }
        }
    }
}

// ---------------- K4: gemm_out (bf16, quarter-staged, + residual) ------------
__global__ __launch_bounds__(512)
void gemm_out(const float* __restrict__ A, const short* __restrict__ Wtab,
              const float* __restrict__ bias, const float* __restrict__ resid,
              void* __restrict__ out, int M) {
    __shared__ short tab[2][16384];                 // 2 x 32KB
    const int tid = threadIdx.x;
    const int l  = tid & 63;
    const int wv = tid >> 6;
    const int lr = l & 15;
    const int lg = l >> 4;
    const int mBase = (blockIdx.x * 8 + wv) * 16;
    const int mRow = mBase + lr;
    const int m = min(mRow, M - 1);
    const char* wsrc = (const char*)Wtab + (size_t)(blockIdx.x & 7) * (TABE * 2);

    auto load_q = [&](int b, int q) {
        #pragma unroll
        for (int it = 0; it < 4; it++) {
            int linear = (it * 512 + tid) * 16;
            const char* src = wsrc + q * 32768 + linear;
            char* dst = (char*)&tab[b][0] + it * 8192 + (tid & 448) * 16;
            gload_lds16(src, dst);
        }
    };

    f32x4 acc[16] = {};
    const float* arow = A + (size_t)m * 256 + lg * 8;

    auto loadAkc = [&](int kc, float4& x0, float4& x1) {
        const float4* p = (const float4*)(arow + kc * 32);
        x0 = p[0]; x1 = p[1];
    };
    auto stepKC = [&](int b, int kk, float4 x0, float4 x1) {
        short8 bfrag = cvt8(x0, x1);
        #pragma unroll
        for (int nt = 0; nt < 16; nt++) {
            short8 wf = *(const short8*)(&tab[b][(kk * 16 + nt) * 512 + l * 8]);
            acc[nt] = __builtin_amdgcn_mfma_f32_16x16x32_bf16(wf, bfrag, acc[nt], 0, 0, 0);
        }
    };

    float4 a0, a1, b0, b1;
    loadAkc(0, a0, a1);
    load_q(0, 0);
    __syncthreads();
    load_q(1, 1);

    loadAkc(1, b0, b1);  stepKC(0, 0, a0, a1);
    loadAkc(2, a0, a1);  stepKC(0, 1, b0, b1);
    __syncthreads();
    load_q(0, 2);
    loadAkc(3, b0, b1);  stepKC(1, 0, a0, a1);
    loadAkc(4, a0, a1);  stepKC(1, 1, b0, b1);
    __syncthreads();
    load_q(1, 3);
    loadAkc(5, b0, b1);  stepKC(0, 0, a0, a1);
    loadAkc(6, a0, a1);  stepKC(0, 1, b0, b1);
    __syncthreads();
    loadAkc(7, b0, b1);  stepKC(1, 0, a0, a1);
                         stepKC(1, 1, b0, b1);

    if (mRow < M) {
        #pragma unroll
        for (int nt = 0; nt < 16; nt++) {
            int n0 = nt * 16 + lg * 4;
            float4 bv = *(const float4*)(bias + n0);
            float4 rz = *(const float4*)(resid + (size_t)mRow * 256 + n0);
            float4 o;
            o.x = acc[nt][0] + bv.x + rz.x; o.y = acc[nt][1] + bv.y + rz.y;
            o.z = acc[nt][2] + bv.z + rz.z; o.w = acc[nt][3] + bv.w + rz.w;
            *(float4*)((float*)out + (size_t)mRow * 256 + n0) = o;
        }
    }
}

// ---------------- K3: head-pinned sampler, 4-lane units + u64 loads ----------
__global__ __launch_bounds__(256)
void sample_kernel(const unsigned char* __restrict__ vproj, const float* __restrict__ offattn,
                   const float* __restrict__ refp, const float* __restrict__ hit,
                   const float* __restrict__ invcnt, float* __restrict__ slots) {
    int bid = blockIdx.x;
    int h = bid & 7;
    int qbase = (bid >> 3) * 64;

    int tid = threadIdx.x;
    int unit = tid >> 2;              // 0..63
    int sub2 = tid & 3;
    int q = qbase + unit;
    if (q >= QN) return;

    const float* oa = offattn + (size_t)q * 192;
    float ox[8], oy[8], aw[8];
    float m = -1e30f;
    #pragma unroll
    for (int p = 0; p < 8; p++) {
        ox[p] = oa[h * 16 + 2 * p];
        oy[p] = oa[h * 16 + 2 * p + 1];
        float lg = oa[128 + h * 8 + p];
        aw[p] = lg;
        m = fmaxf(m, lg);
    }
    float s = 0.f;
    #pragma unroll
    for (int p = 0; p < 8; p++) { aw[p] = __expf(aw[p] - m); s += aw[p]; }
    float is = 1.f / s;
    #pragma unroll
    for (int p = 0; p < 8; p++) aw[p] *= is;

    float a0 = 0.f, a1 = 0.f, a2 = 0.f, a3 = 0.f;
    float a4 = 0.f, a5 = 0.f, a6 = 0.f, a7 = 0.f;
    const unsigned long long* plane =
        (const unsigned long long*)vproj + (size_t)h * MROW * 4 + sub2;

    auto acc8 = [&](unsigned long long u, float w) {
        unsigned ulo = (unsigned)u, uhi = (unsigned)(u >> 32);
#if __has_builtin(__builtin_amdgcn_cvt_pk_f32_fp8)
        floatx2 f0 = __builtin_amdgcn_cvt_pk_f32_fp8((int)ulo, false);
        floatx2 f1 = __builtin_amdgcn_cvt_pk_f32_fp8((int)ulo, true);
        floatx2 f2 = __builtin_amdgcn_cvt_pk_f32_fp8((int)uhi, false);
        floatx2 f3 = __builtin_amdgcn_cvt_pk_f32_fp8((int)uhi, true);
        a0 = fmaf(w, f0.x, a0); a1 = fmaf(w, f0.y, a1);
        a2 = fmaf(w, f1.x, a2); a3 = fmaf(w, f1.y, a3);
        a4 = fmaf(w, f2.x, a4); a5 = fmaf(w, f2.y, a5);
        a6 = fmaf(w, f3.x, a6); a7 = fmaf(w, f3.y, a7);
#else
        a0 = fmaf(w, e4m3f_manual(ulo & 255), a0);
        a1 = fmaf(w, e4m3f_manual((ulo >> 8) & 255), a1);
        a2 = fmaf(w, e4m3f_manual((ulo >> 16) & 255), a2);
        a3 = fmaf(w, e4m3f_manual(ulo >> 24), a3);
        a4 = fmaf(w, e4m3f_manual(uhi & 255), a4);
        a5 = fmaf(w, e4m3f_manual((uhi >> 8) & 255), a5);
        a6 = fmaf(w, e4m3f_manual((uhi >> 16) & 255), a6);
        a7 = fmaf(w, e4m3f_manual(uhi >> 24), a7);
#endif
    };

    for (int c = 0; c < CAMS; c++) {
        if (hit[c * QN + q] == 0.f) continue;
        const float* rp = refp + (size_t)(c * QN + q) * 8;
        float rx[4], ry[4];
        #pragma unroll
        for (int d = 0; d < 4; d++) {
            rx[d] = rp[2 * d]     * (float)WW - 0.5f;
            ry[d] = rp[2 * d + 1] * (float)HH - 0.5f;
        }
        const unsigned long long* vc = plane + (size_t)c * NV * 4;
        #pragma unroll
        for (int p = 0; p < 8; p++) {
            float x = rx[p & 3] + ox[p];
            float y = ry[p & 3] + oy[p];
            float xf = floorf(x), yf = floorf(y);
            float fx = x - xf, fy = y - yf;
            int x0 = (int)xf, y0 = (int)yf;
            int xc0 = min(max(x0, 0), WW - 1), xc1 = min(max(x0 + 1, 0), WW - 1);
            int yc0 = min(max(y0, 0), HH - 1), yc1 = min(max(y0 + 1, 0), HH - 1);
            float vx0 = ((unsigned)x0 < (unsigned)WW) ? 1.f : 0.f;
            float vx1 = ((unsigned)(x0 + 1) < (unsigned)WW) ? 1.f : 0.f;
            float vy0 = ((unsigned)y0 < (unsigned)HH) ? 1.f : 0.f;
            float vy1 = ((unsigned)(y0 + 1) < (unsigned)HH) ? 1.f : 0.f;
            float wp = aw[p];
            float wx0 = (1.f - fx) * vx0 * wp, wx1 = fx * vx1 * wp;
            float wy0 = (1.f - fy) * vy0,      wy1 = fy * vy1;
            int b0 = yc0 * WW, b1 = yc1 * WW;
            unsigned long long u00 = vc[(size_t)(b0 + xc0) * 4];
            unsigned long long u10 = vc[(size_t)(b0 + xc1) * 4];
            unsigned long long u01 = vc[(size_t)(b1 + xc0) * 4];
            unsigned long long u11 = vc[(size_t)(b1 + xc1) * 4];
            acc8(u00, wx0 * wy0);
            acc8(u10, wx1 * wy0);
            acc8(u01, wx0 * wy1);
            acc8(u11, wx1 * wy1);
        }
    }
    float ic = invcnt[q];
    float* sp = slots + (size_t)q * 256 + h * 32 + sub2 * 8;
    float4 o0; o0.x = a0 * ic; o0.y = a1 * ic; o0.z = a2 * ic; o0.w = a3 * ic;
    float4 o1; o1.x = a4 * ic; o1.y = a5 * ic; o1.z = a6 * ic; o1.w = a7 * ic;
    *(float4*)sp = o0;
    *(float4*)(sp + 4) = o1;
}

extern "C" void kernel_launch(void* const* d_in, const int* in_sizes, int n_in,
                              void* d_out, int out_size, void* d_ws, size_t ws_size,
                              hipStream_t stream) {
    const float* query   = (const float*)d_in[0];
    const float* value   = (const float*)d_in[2];
    const float* refp    = (const float*)d_in[3];
    const void*  mask    = d_in[4];
    const float* w_value = (const float*)d_in[7];
    const float* b_value = (const float*)d_in[8];
    const float* w_off   = (const float*)d_in[9];
    const float* b_off   = (const float*)d_in[10];
    const float* w_attn  = (const float*)d_in[11];
    const float* b_attn  = (const float*)d_in[12];
    const float* w_out   = (const float*)d_in[13];
    const float* b_out   = (const float*)d_in[14];
    float* out = (float*)d_out;

    char* w = (char*)d_ws;
    size_t o = 0;
    auto carve = [&](size_t bytes) { size_t r = o; o = (o + bytes + 255) & ~(size_t)255; return r; };
    int*   flag    = (int*)  (w + carve(4));
    float* hitv    = (float*)(w + carve(sizeof(float) * CAMS * QN));
    float* invc    = (float*)(w + carve(sizeof(float) * QN));
    unsigned char* tv8 = (unsigned char*)(w + carve((size_t)TABE * 8));
    short* toa     = (short*)(w + carve(2 * TABE * 8));
    short* tout    = (short*)(w + carve(2 * TABE * 8));
    float* biasOA  = (float*)(w + carve(sizeof(float) * 192));
    unsigned* value8 = (unsigned*)(w + carve((size_t)MROW * 256));
    unsigned char* vproj = (unsigned char*)(w + carve((size_t)MROW * 256));
    float* offattn = (float*)(w + carve(sizeof(float) * QN * 192));
    float* slots   = (float*)(w + carve(sizeof(float) * QN * 256));

    detect_kernel<<<1, 256, 0, stream>>>((const unsigned char*)mask, flag);
    prep_hit_kernel<<<NPREP + NHIT + NCVT, 256, 0, stream>>>(
        w_value, w_off, w_attn, w_out, b_off, b_attn,
        tv8, toa, tout, biasOA, mask, flag, hitv, invc,
        value, value8);

    gemm_v_oa<<<NVB + NOAB, 512, 0, stream>>>(
        (const unsigned char*)value8, tv8, b_value, query, toa, biasOA,
        vproj, offattn, MROW);

    sample_kernel<<<8 * 157, 256, 0, stream>>>(
        vproj, offattn, refp, hitv, invc, slots);

    gemm_out<<<(QN + 127) / 128, 512, 0, stream>>>(slots, tout, b_out, query, out, QN);
}

// Round 27
// 137.523 us; speedup vs baseline: 1.0760x; 1.0760x over previous
//
#include <hip/hip_runtime.h>
#include <hip/hip_bf16.h>

// SpatialCrossAttention (BEVFormer SCA) fused pipeline for MI355X/gfx950.
// R27 = R25 verbatim (measured best: 138.3us). All components at their
// best-measured forms; every structural lever tested R2-R26 and resolved.
//  K0 detect   : infer bev_mask storage layout (u8 / i32 / f32)
//  K1 prep_hit : FUSED tables + bias | hit/invcnt
//  K2 gemm_v_oa: FUSED gemm_v (fp8 MFMA, 64KB table in LDS, one barrier,
//                head-planar out; 85us floor) | gemm_oa (bf16 quarter-staged)
//  K3 sample   : head-pinned blocks; 4-lane units + u64 loads
//  K4 gemm_out : bf16 quarter-staged + residual

__device__ __forceinline__ void gload_lds16(const void* g, void* l) {
    __builtin_amdgcn_global_load_lds(
        (const __attribute__((address_space(1))) unsigned*)g,
        (__attribute__((address_space(3))) unsigned*)l, 16, 0, 0);
}

typedef __attribute__((ext_vector_type(8))) short short8;
typedef __attribute__((ext_vector_type(4))) float f32x4;
typedef __attribute__((ext_vector_type(2))) float floatx2;

__device__ __forceinline__ short f2bf(float f) {
    union { float f; unsigned u; } c; c.f = f;
    unsigned u = c.u;
    unsigned r = (u + 0x7FFFu + ((u >> 16) & 1u)) >> 16;  // RNE
    return (short)r;
}

// ---- fp8 e4m3fn decode/encode: HW cvt on gfx950, manual fallback ----
__device__ __forceinline__ float e4m3f_manual(unsigned b) {
    unsigned s = (b & 0x80u) << 24;
    unsigned e = (b >> 3) & 15u;
    unsigned m = b & 7u;
    if (e) return __uint_as_float(s | ((e + 120u) << 23) | (m << 20));
    return __uint_as_float(s | __float_as_uint((float)m * 0x1p-9f));
}
__device__ __forceinline__ unsigned char f2e4m3_manual(float x) {
    unsigned u = __float_as_uint(x);
    unsigned s = (u >> 24) & 0x80u;
    float ax = fabsf(x);
    if (!(ax > 0x1p-10f)) return (unsigned char)s;
    if (ax >= 440.f) return (unsigned char)(s | 0x7Eu);
    unsigned au = u & 0x7FFFFFFFu;
    int e = (int)(au >> 23) - 127;
    if (e >= -6) {
        unsigned r = au + 0x7FFFFu + ((au >> 20) & 1u);
        e = (int)(r >> 23) - 127;
        unsigned m = (r >> 20) & 7u;
        if (e > 8) return (unsigned char)(s | 0x7Eu);
        return (unsigned char)(s | (unsigned)((e + 7) << 3) | m);
    } else {
        int m = (int)rintf(ax * 512.f);
        return (unsigned char)(s | (unsigned)m);
    }
}
__device__ __forceinline__ unsigned char enc_fp8(float v) {
#if __has_builtin(__builtin_amdgcn_cvt_pk_fp8_f32)
    return (unsigned char)(__builtin_amdgcn_cvt_pk_fp8_f32(v, v, 0, false) & 0xFF);
#else
    return f2e4m3_manual(v);
#endif
}

static constexpr int QN   = 10000;
static constexpr int CAMS = 6;
static constexpr int NV   = 23200;   // 116*200
static constexpr int HH   = 116;
static constexpr int WW   = 200;
static constexpr int MROW = CAMS * NV;  // 139200
static constexpr int TABE = 65536;      // entries per table copy
static constexpr int NVB  = (MROW + 127) / 128;    // 1088 gemm_v blocks
static constexpr int NOAB = (QN + 127) / 128;      // 79 gemm_oa blocks
static constexpr int NPREP = 769;                  // prep blocks
static constexpr int NHIT  = (QN + 255) / 256;     // 40 hit blocks

// ---------------- K0: mask layout detect (16KB scan) ----------------
__global__ void detect_kernel(const unsigned char* __restrict__ mask, int* __restrict__ flag) {
    __shared__ unsigned s12[256], s3[256];
    unsigned o12 = 0, o3 = 0;
    for (int i = threadIdx.x; i < 16384; i += 256) {
        unsigned char b = mask[i];
        int m = i & 3;
        if (m == 1 || m == 2) o12 |= b;
        else if (m == 3) o3 |= b;
    }
    s12[threadIdx.x] = o12; s3[threadIdx.x] = o3;
    __syncthreads();
    if (threadIdx.x == 0) {
        unsigned a = 0, b = 0;
        for (int i = 0; i < 256; i++) { a |= s12[i]; b |= s3[i]; }
        *flag = a ? 0 : (b ? 2 : 1);  // 0=u8, 1=i32, 2=f32
    }
}

// ---------------- K1: FUSED prep (blocks 0..768) + hit (blocks 769..) --------
__global__ void prep_hit_kernel(const float* __restrict__ wv, const float* __restrict__ woff,
                                const float* __restrict__ wattn, const float* __restrict__ wout,
                                const float* __restrict__ boff, const float* __restrict__ battn,
                                unsigned char* __restrict__ tv8, short* __restrict__ toa,
                                short* __restrict__ tout, float* __restrict__ biasOA,
                                const void* __restrict__ mask, const int* __restrict__ flag,
                                float* __restrict__ hit, float* __restrict__ invcnt) {
    int bid = blockIdx.x;
    if (bid < NPREP) {
        int id = bid * 256 + threadIdx.x;
        if (id < 3 * TABE) {
            int t = id >> 16;
            int e = id & 65535;
            int j = e & 7, l = (e >> 3) & 63, nt = (e >> 9) & 15, kc = e >> 13;
            int k = kc * 32 + ((l >> 4) << 3) + j;
            int col = nt * 16 + (l & 15);
            if (t == 0) {
                unsigned char b = enc_fp8(wv[k * 256 + col]);
                #pragma unroll
                for (int c = 0; c < 8; c++) tv8[c * TABE + e] = b;
            } else {
                float v;
                if (t == 1) v = (col < 128) ? woff[k * 128 + col]
                                  : (col < 192 ? wattn[k * 64 + (col - 128)] : 0.f);
                else        v = wout[k * 256 + col];
                short* dst = (t == 1) ? toa : tout;
                short bv = f2bf(v);
                #pragma unroll
                for (int c = 0; c < 8; c++) dst[c * TABE + e] = bv;
            }
        } else {
            int i = id - 3 * TABE;
            if (i < 192) biasOA[i] = (i < 128) ? boff[i] : battn[i - 128];
        }
    } else {
        int q = (bid - NPREP) * 256 + threadIdx.x;
        if (q >= QN) return;
        int f = *flag;
        int cnt = 0;
        for (int c = 0; c < CAMS; c++) {
            bool any = false;
            #pragma unroll
            for (int d = 0; d < 4; d++) {
                size_t i = (size_t)(c * QN + q) * 4 + d;
                bool b;
                if (f == 0)      b = ((const unsigned char*)mask)[i] != 0;
                else if (f == 1) b = ((const int*)mask)[i] != 0;
                else             b = ((const float*)mask)[i] != 0.f;
                any |= b;
            }
            hit[c * QN + q] = any ? 1.f : 0.f;
            cnt += any ? 1 : 0;
        }
        invcnt[q] = 1.f / (float)(cnt > 0 ? cnt : 1);
    }
}

__device__ __forceinline__ short8 cvt8(float4 x0, float4 x1) {
    unsigned u0, u1, u2, u3;
    asm("v_cvt_pk_bf16_f32 %0, %1, %2" : "=v"(u0) : "v"(x0.x), "v"(x0.y));
    asm("v_cvt_pk_bf16_f32 %0, %1, %2" : "=v"(u1) : "v"(x0.z), "v"(x0.w));
    asm("v_cvt_pk_bf16_f32 %0, %1, %2" : "=v"(u2) : "v"(x1.x), "v"(x1.y));
    asm("v_cvt_pk_bf16_f32 %0, %1, %2" : "=v"(u3) : "v"(x1.z), "v"(x1.w));
    union { unsigned u[4]; short8 s8; } uu;
    uu.u[0] = u0; uu.u[1] = u1; uu.u[2] = u2; uu.u[3] = u3;
    return uu.s8;
}

__device__ __forceinline__ long long pk8fp8(float4 x0, float4 x1) {
#if __has_builtin(__builtin_amdgcn_cvt_pk_fp8_f32)
    unsigned lo = (unsigned)__builtin_amdgcn_cvt_pk_fp8_f32(x0.x, x0.y, 0, false);
    lo = (unsigned)__builtin_amdgcn_cvt_pk_fp8_f32(x0.z, x0.w, (int)lo, true);
    unsigned hi = (unsigned)__builtin_amdgcn_cvt_pk_fp8_f32(x1.x, x1.y, 0, false);
    hi = (unsigned)__builtin_amdgcn_cvt_pk_fp8_f32(x1.z, x1.w, (int)hi, true);
#else
    unsigned lo = (unsigned)f2e4m3_manual(x0.x) | ((unsigned)f2e4m3_manual(x0.y) << 8)
                | ((unsigned)f2e4m3_manual(x0.z) << 16) | ((unsigned)f2e4m3_manual(x0.w) << 24);
    unsigned hi = (unsigned)f2e4m3_manual(x1.x) | ((unsigned)f2e4m3_manual(x1.y) << 8)
                | ((unsigned)f2e4m3_manual(x1.z) << 16) | ((unsigned)f2e4m3_manual(x1.w) << 24);
#endif
    return (long long)(((unsigned long long)hi << 32) | lo);
}

// ---------------- K2: FUSED gemm_v (blocks < NVB) + gemm_oa (rest) -----------
__global__ __launch_bounds__(512)
void gemm_v_oa(const float* __restrict__ A, const unsigned char* __restrict__ Wtab8,
               const float* __restrict__ biasV,
               const float* __restrict__ Q, const short* __restrict__ WtabOA,
               const float* __restrict__ biasOA,
               void* __restrict__ vout, void* __restrict__ oaout, int M) {
    __shared__ __align__(16) char smem[65536];
    const int tid = threadIdx.x;
    const int l  = tid & 63;
    const int wv = tid >> 6;
    const int lr = l & 15;
    const int lg = l >> 4;

    if (blockIdx.x < NVB) {
        // ---------------- gemm_v body ----------------
        unsigned char* tab = (unsigned char*)smem;
        const int mBase = (blockIdx.x * 8 + wv) * 16;
        const int mRow = mBase + lr;
        const int m = min(mRow, M - 1);
        const unsigned char* wsrc = Wtab8 + (size_t)(blockIdx.x & 7) * TABE;

        #pragma unroll
        for (int it = 0; it < 8; it++) {
            gload_lds16(wsrc + (it * 512 + tid) * 16,
                        tab + it * 8192 + (tid & 448) * 16);   // wave-uniform dst
        }

        const float* arow = A + (size_t)m * 256 + lg * 8;
        f32x4 acc[16] = {};

        float4 a0, a1, b0, b1;
        { const float4* p = (const float4*)(arow); a0 = p[0]; a1 = p[1]; }
        __syncthreads();                            // table visible; ONLY barrier

        auto stepKC = [&](int kc, float4 x0, float4 x1) {
            long long bfrag = pk8fp8(x0, x1);
            #pragma unroll
            for (int nt = 0; nt < 16; nt++) {
                long long wf = *(const long long*)(&tab[(kc * 16 + nt) * 512 + l * 8]);
                acc[nt] = __builtin_amdgcn_mfma_f32_16x16x32_fp8_fp8(wf, bfrag, acc[nt], 0, 0, 0);
            }
        };

        #pragma unroll
        for (int kc = 0; kc < 8; kc += 2) {
            if (kc + 1 < 8) { const float4* p = (const float4*)(arow + (kc + 1) * 32); b0 = p[0]; b1 = p[1]; }
            stepKC(kc, a0, a1);
            if (kc + 2 < 8) { const float4* p = (const float4*)(arow + (kc + 2) * 32); a0 = p[0]; a1 = p[1]; }
            stepKC(kc + 1, b0, b1);
        }

        if (mRow < M) {
            #pragma unroll
            for (int nt = 0; nt < 16; nt++) {
                int n0 = nt * 16 + lg * 4;
                float4 bv = *(const float4*)(biasV + n0);
                float v0 = acc[nt][0] + bv.x, v1 = acc[nt][1] + bv.y;
                float v2 = acc[nt][2] + bv.z, v3 = acc[nt][3] + bv.w;
                unsigned pk;
#if __has_builtin(__builtin_amdgcn_cvt_pk_fp8_f32)
                pk = __builtin_amdgcn_cvt_pk_fp8_f32(v0, v1, 0, false);
                pk = __builtin_amdgcn_cvt_pk_fp8_f32(v2, v3, pk, true);
#else
                pk = (unsigned)f2e4m3_manual(v0) | ((unsigned)f2e4m3_manual(v1) << 8)
                   | ((unsigned)f2e4m3_manual(v2) << 16) | ((unsigned)f2e4m3_manual(v3) << 24);
#endif
                // head-planar: plane nt>>1, slot (nt&1)*4+lg of row mRow
                ((unsigned*)vout)[(size_t)(nt >> 1) * MROW * 8 + (size_t)mRow * 8
                                  + (nt & 1) * 4 + lg] = pk;
            }
        }
    } else {
        // ---------------- gemm_oa body (bf16, quarter-staged, 192 cols) ------
        short (*tab)[16384] = (short (*)[16384])smem;
        const int bid = blockIdx.x - NVB;
        const int mBase = (bid * 8 + wv) * 16;
        const int mRow = mBase + lr;
        const int m = min(mRow, QN - 1);
        const char* wsrc = (const char*)WtabOA + (size_t)(bid & 7) * (TABE * 2);

        auto load_q = [&](int b, int q) {
            #pragma unroll
            for (int it = 0; it < 4; it++) {
                int linear = (it * 512 + tid) * 16;
                const char* src = wsrc + q * 32768 + linear;
                char* dst = (char*)&tab[b][0] + it * 8192 + (tid & 448) * 16;
                gload_lds16(src, dst);
            }
        };

        f32x4 acc[12] = {};
        const float* arow = Q + (size_t)m * 256 + lg * 8;

        auto loadAkc = [&](int kc, float4& x0, float4& x1) {
            const float4* p = (const float4*)(arow + kc * 32);
            x0 = p[0]; x1 = p[1];
        };
        auto stepKC = [&](int b, int kk, float4 x0, float4 x1) {
            short8 bfrag = cvt8(x0, x1);
            #pragma unroll
            for (int nt = 0; nt < 12; nt++) {
                short8 wf = *(const short8*)(&tab[b][(kk * 16 + nt) * 512 + l * 8]);
                acc[nt] = __builtin_amdgcn_mfma_f32_16x16x32_bf16(wf, bfrag, acc[nt], 0, 0, 0);
            }
        };

        float4 a0, a1, b0, b1;
        loadAkc(0, a0, a1);
        load_q(0, 0);
        __syncthreads();
        load_q(1, 1);

        loadAkc(1, b0, b1);  stepKC(0, 0, a0, a1);
        loadAkc(2, a0, a1);  stepKC(0, 1, b0, b1);
        __syncthreads();
        load_q(0, 2);
        loadAkc(3, b0, b1);  stepKC(1, 0, a0, a1);
        loadAkc(4, a0, a1);  stepKC(1, 1, b0, b1);
        __syncthreads();
        load_q(1, 3);
        loadAkc(5, b0, b1);  stepKC(0, 0, a0, a1);
        loadAkc(6, a0, a1);  stepKC(0, 1, b0, b1);
        __syncthreads();
        loadAkc(7, b0, b1);  stepKC(1, 0, a0, a1);
                             stepKC(1, 1, b0, b1);

        if (mRow < QN) {
            #pragma unroll
            for (int nt = 0; nt < 12; nt++) {
                int n0 = nt * 16 + lg * 4;
                float4 bv = *(const float4*)(biasOA + n0);
                float4 o;
                o.x = acc[nt][0] + bv.x; o.y = acc[nt][1] + bv.y;
                o.z = acc[nt][2] + bv.z; o.w = acc[nt][3] + bv.w;
                *(float4*)((float*)oaout + (size_t)mRow * 192 + n0) = o;
            }
        }
    }
}

// ---------------- K4: gemm_out (bf16, quarter-staged, + residual) ------------
__global__ __launch_bounds__(512)
void gemm_out(const float* __restrict__ A, const short* __restrict__ Wtab,
              const float* __restrict__ bias, const float* __restrict__ resid,
              void* __restrict__ out, int M) {
    __shared__ short tab[2][16384];                 // 2 x 32KB
    const int tid = threadIdx.x;
    const int l  = tid & 63;
    const int wv = tid >> 6;
    const int lr = l & 15;
    const int lg = l >> 4;
    const int mBase = (blockIdx.x * 8 + wv) * 16;
    const int mRow = mBase + lr;
    const int m = min(mRow, M - 1);
    const char* wsrc = (const char*)Wtab + (size_t)(blockIdx.x & 7) * (TABE * 2);

    auto load_q = [&](int b, int q) {
        #pragma unroll
        for (int it = 0; it < 4; it++) {
            int linear = (it * 512 + tid) * 16;
            const char* src = wsrc + q * 32768 + linear;
            char* dst = (char*)&tab[b][0] + it * 8192 + (tid & 448) * 16;
            gload_lds16(src, dst);
        }
    };

    f32x4 acc[16] = {};
    const float* arow = A + (size_t)m * 256 + lg * 8;

    auto loadAkc = [&](int kc, float4& x0, float4& x1) {
        const float4* p = (const float4*)(arow + kc * 32);
        x0 = p[0]; x1 = p[1];
    };
    auto stepKC = [&](int b, int kk, float4 x0, float4 x1) {
        short8 bfrag = cvt8(x0, x1);
        #pragma unroll
        for (int nt = 0; nt < 16; nt++) {
            short8 wf = *(const short8*)(&tab[b][(kk * 16 + nt) * 512 + l * 8]);
            acc[nt] = __builtin_amdgcn_mfma_f32_16x16x32_bf16(wf, bfrag, acc[nt], 0, 0, 0);
        }
    };

    float4 a0, a1, b0, b1;
    loadAkc(0, a0, a1);
    load_q(0, 0);
    __syncthreads();
    load_q(1, 1);

    loadAkc(1, b0, b1);  stepKC(0, 0, a0, a1);
    loadAkc(2, a0, a1);  stepKC(0, 1, b0, b1);
    __syncthreads();
    load_q(0, 2);
    loadAkc(3, b0, b1);  stepKC(1, 0, a0, a1);
    loadAkc(4, a0, a1);  stepKC(1, 1, b0, b1);
    __syncthreads();
    load_q(1, 3);
    loadAkc(5, b0, b1);  stepKC(0, 0, a0, a1);
    loadAkc(6, a0, a1);  stepKC(0, 1, b0, b1);
    __syncthreads();
    loadAkc(7, b0, b1);  stepKC(1, 0, a0, a1);
                         stepKC(1, 1, b0, b1);

    if (mRow < M) {
        #pragma unroll
        for (int nt = 0; nt < 16; nt++) {
            int n0 = nt * 16 + lg * 4;
            float4 bv = *(const float4*)(bias + n0);
            float4 rz = *(const float4*)(resid + (size_t)mRow * 256 + n0);
            float4 o;
            o.x = acc[nt][0] + bv.x + rz.x; o.y = acc[nt][1] + bv.y + rz.y;
            o.z = acc[nt][2] + bv.z + rz.z; o.w = acc[nt][3] + bv.w + rz.w;
            *(float4*)((float*)out + (size_t)mRow * 256 + n0) = o;
        }
    }
}

// ---------------- K3: head-pinned sampler, 4-lane units + u64 loads ----------
__global__ __launch_bounds__(256)
void sample_kernel(const unsigned char* __restrict__ vproj, const float* __restrict__ offattn,
                   const float* __restrict__ refp, const float* __restrict__ hit,
                   const float* __restrict__ invcnt, float* __restrict__ slots) {
    int bid = blockIdx.x;
    int h = bid & 7;
    int qbase = (bid >> 3) * 64;

    int tid = threadIdx.x;
    int unit = tid >> 2;              // 0..63
    int sub2 = tid & 3;
    int q = qbase + unit;
    if (q >= QN) return;

    const float* oa = offattn + (size_t)q * 192;
    float ox[8], oy[8], aw[8];
    float m = -1e30f;
    #pragma unroll
    for (int p = 0; p < 8; p++) {
        ox[p] = oa[h * 16 + 2 * p];
        oy[p] = oa[h * 16 + 2 * p + 1];
        float lg = oa[128 + h * 8 + p];
        aw[p] = lg;
        m = fmaxf(m, lg);
    }
    float s = 0.f;
    #pragma unroll
    for (int p = 0; p < 8; p++) { aw[p] = __expf(aw[p] - m); s += aw[p]; }
    float is = 1.f / s;
    #pragma unroll
    for (int p = 0; p < 8; p++) aw[p] *= is;

    float a0 = 0.f, a1 = 0.f, a2 = 0.f, a3 = 0.f;
    float a4 = 0.f, a5 = 0.f, a6 = 0.f, a7 = 0.f;
    const unsigned long long* plane =
        (const unsigned long long*)vproj + (size_t)h * MROW * 4 + sub2;

    auto acc8 = [&](unsigned long long u, float w) {
        unsigned ulo = (unsigned)u, uhi = (unsigned)(u >> 32);
#if __has_builtin(__builtin_amdgcn_cvt_pk_f32_fp8)
        floatx2 f0 = __builtin_amdgcn_cvt_pk_f32_fp8((int)ulo, false);
        floatx2 f1 = __builtin_amdgcn_cvt_pk_f32_fp8((int)ulo, true);
        floatx2 f2 = __builtin_amdgcn_cvt_pk_f32_fp8((int)uhi, false);
        floatx2 f3 = __builtin_amdgcn_cvt_pk_f32_fp8((int)uhi, true);
        a0 = fmaf(w, f0.x, a0); a1 = fmaf(w, f0.y, a1);
        a2 = fmaf(w, f1.x, a2); a3 = fmaf(w, f1.y, a3);
        a4 = fmaf(w, f2.x, a4); a5 = fmaf(w, f2.y, a5);
        a6 = fmaf(w, f3.x, a6); a7 = fmaf(w, f3.y, a7);
#else
        a0 = fmaf(w, e4m3f_manual(ulo & 255), a0);
        a1 = fmaf(w, e4m3f_manual((ulo >> 8) & 255), a1);
        a2 = fmaf(w, e4m3f_manual((ulo >> 16) & 255), a2);
        a3 = fmaf(w, e4m3f_manual(ulo >> 24), a3);
        a4 = fmaf(w, e4m3f_manual(uhi & 255), a4);
        a5 = fmaf(w, e4m3f_manual((uhi >> 8) & 255), a5);
        a6 = fmaf(w, e4m3f_manual((uhi >> 16) & 255), a6);
        a7 = fmaf(w, e4m3f_manual(uhi >> 24), a7);
#endif
    };

    for (int c = 0; c < CAMS; c++) {
        if (hit[c * QN + q] == 0.f) continue;
        const float* rp = refp + (size_t)(c * QN + q) * 8;
        float rx[4], ry[4];
        #pragma unroll
        for (int d = 0; d < 4; d++) {
            rx[d] = rp[2 * d]     * (float)WW - 0.5f;
            ry[d] = rp[2 * d + 1] * (float)HH - 0.5f;
        }
        const unsigned long long* vc = plane + (size_t)c * NV * 4;
        #pragma unroll
        for (int p = 0; p < 8; p++) {
            float x = rx[p & 3] + ox[p];
            float y = ry[p & 3] + oy[p];
            float xf = floorf(x), yf = floorf(y);
            float fx = x - xf, fy = y - yf;
            int x0 = (int)xf, y0 = (int)yf;
            int xc0 = min(max(x0, 0), WW - 1), xc1 = min(max(x0 + 1, 0), WW - 1);
            int yc0 = min(max(y0, 0), HH - 1), yc1 = min(max(y0 + 1, 0), HH - 1);
            float vx0 = ((unsigned)x0 < (unsigned)WW) ? 1.f : 0.f;
            float vx1 = ((unsigned)(x0 + 1) < (unsigned)WW) ? 1.f : 0.f;
            float vy0 = ((unsigned)y0 < (unsigned)HH) ? 1.f : 0.f;
            float vy1 = ((unsigned)(y0 + 1) < (unsigned)HH) ? 1.f : 0.f;
            float wp = aw[p];
            float wx0 = (1.f - fx) * vx0 * wp, wx1 = fx * vx1 * wp;
            float wy0 = (1.f - fy) * vy0,      wy1 = fy * vy1;
            int b0 = yc0 * WW, b1 = yc1 * WW;
            unsigned long long u00 = vc[(size_t)(b0 + xc0) * 4];
            unsigned long long u10 = vc[(size_t)(b0 + xc1) * 4];
            unsigned long long u01 = vc[(size_t)(b1 + xc0) * 4];
            unsigned long long u11 = vc[(size_t)(b1 + xc1) * 4];
            acc8(u00, wx0 * wy0);
            acc8(u10, wx1 * wy0);
            acc8(u01, wx0 * wy1);
            acc8(u11, wx1 * wy1);
        }
    }
    float ic = invcnt[q];
    float* sp = slots + (size_t)q * 256 + h * 32 + sub2 * 8;
    float4 o0; o0.x = a0 * ic; o0.y = a1 * ic; o0.z = a2 * ic; o0.w = a3 * ic;
    float4 o1; o1.x = a4 * ic; o1.y = a5 * ic; o1.z = a6 * ic; o1.w = a7 * ic;
    *(float4*)sp = o0;
    *(float4*)(sp + 4) = o1;
}

extern "C" void kernel_launch(void* const* d_in, const int* in_sizes, int n_in,
                              void* d_out, int out_size, void* d_ws, size_t ws_size,
                              hipStream_t stream) {
    const float* query   = (const float*)d_in[0];
    const float* value   = (const float*)d_in[2];
    const float* refp    = (const float*)d_in[3];
    const void*  mask    = d_in[4];
    const float* w_value = (const float*)d_in[7];
    const float* b_value = (const float*)d_in[8];
    const float* w_off   = (const float*)d_in[9];
    const float* b_off   = (const float*)d_in[10];
    const float* w_attn  = (const float*)d_in[11];
    const float* b_attn  = (const float*)d_in[12];
    const float* w_out   = (const float*)d_in[13];
    const float* b_out   = (const float*)d_in[14];
    float* out = (float*)d_out;

    char* w = (char*)d_ws;
    size_t o = 0;
    auto carve = [&](size_t bytes) { size_t r = o; o = (o + bytes + 255) & ~(size_t)255; return r; };
    int*   flag    = (int*)  (w + carve(4));
    float* hitv    = (float*)(w + carve(sizeof(float) * CAMS * QN));
    float* invc    = (float*)(w + carve(sizeof(float) * QN));
    unsigned char* tv8 = (unsigned char*)(w + carve((size_t)TABE * 8));
    short* toa     = (short*)(w + carve(2 * TABE * 8));
    short* tout    = (short*)(w + carve(2 * TABE * 8));
    float* biasOA  = (float*)(w + carve(sizeof(float) * 192));
    unsigned char* vproj = (unsigned char*)(w + carve((size_t)MROW * 256));
    float* offattn = (float*)(w + carve(sizeof(float) * QN * 192));
    float* slots   = (float*)(w + carve(sizeof(float) * QN * 256));

    detect_kernel<<<1, 256, 0, stream>>>((const unsigned char*)mask, flag);
    prep_hit_kernel<<<NPREP + NHIT, 256, 0, stream>>>(
        w_value, w_off, w_attn, w_out, b_off, b_attn,
        tv8, toa, tout, biasOA, mask, flag, hitv, invc);

    gemm_v_oa<<<NVB + NOAB, 512, 0, stream>>>(
        value, tv8, b_value, query, toa, biasOA, vproj, offattn, MROW);

    sample_kernel<<<8 * 157, 256, 0, stream>>>(
        vproj, offattn, refp, hitv, invc, slots);

    gemm_out<<<(QN + 127) / 128, 512, 0, stream>>>(slots, tout, b_out, query, out, QN);
}